// Round 18
// baseline (113.383 us; speedup 1.0000x reference)
//
#include <hip/hip_runtime.h>

// 4 rays per wave: 16 lanes/ray, 4 consecutive samples per lane (R7 base).
// R8: analytic inverse scatter. R9: fused affine scan — NEUTRAL.
// R17/R18: multipass diagnostics: VALUBusy 83%, VGPR 28, FETCH 34.8MB =>
//   VALU-ISSUE-BOUND. Calibration: ~0.027us per 2-cy op; trans ~4x.
// R19: exp2 fold + uniform-dz — WIN 114.54->113.78 (matched model).
// R20: 8 lanes/ray — REGRESSION 114.47, reverted.
// R21: ratio-sigmoid alpha=((B-A)+eQ)/((1+B)+eQ) — WIN 113.78->113.04
//   (predicted -0.5..-0.9, measured -0.74; model 3-for-3).
// R25: tail op-diet (same lever class):
//   (a) scale-fold: cr2 = ds*G with G = rden*q, q = -hds2 > 0. min/med3
//       commute with positive scale; c2 = med3(min(prev2,cr2),-1000q,0)*insf;
//       aarg = min(smid+c2,60), barg = min(smid-c2,60). Kills the per-sample
//       *hds2 mul (exact mod one pre-rounding of G; clamp boundary scales
//       consistently).
//   (b) explicit fmed3f for the clamp (1 op vs fmax+fmin).
//   (c) t_part[0]==0 always => cvec.x = Sk*rtot (-1 fma).
//   Est -5..-9 ops => -0.15..-0.35us. If neutral: op-diet exhausted,
//   structural floor reached.
// R26: resubmit of R25 — GPU acquisition timed out; R25 never measured.
//   Re-audit: fmed3f clamp semantics, scale-fold signs, cvec.x fold all ok.

template<int CTRL, int RM>
__device__ __forceinline__ float dpp_movf(float old, float x) {
    return __int_as_float(__builtin_amdgcn_update_dpp(
        __float_as_int(old), __float_as_int(x), CTRL, RM, 0xF, false));
}
template<int CTRL, int RM>
__device__ __forceinline__ int dpp_movi(int old, int x) {
    return __builtin_amdgcn_update_dpp(old, x, CTRL, RM, 0xF, false);
}
// row_shr:N = 0x110|N (row = 16 lanes), wave_shl:1 = 0x130 (validated R1-R21).
__device__ __forceinline__ float fast_rcp(float x) { return __builtin_amdgcn_rcpf(x); }
__device__ __forceinline__ float bperm(float x, int srclane) {
    return __int_as_float(__builtin_amdgcn_ds_bpermute(srclane << 2, __float_as_int(x)));
}

__global__ __launch_bounds__(256, 8) void neus_upsample_kernel(
    const float* __restrict__ rays_o,
    const float* __restrict__ rays_d,
    const float* __restrict__ z_vals,
    const float* __restrict__ sdf,
    const int*   __restrict__ inv_s_ptr,
    float*       __restrict__ out,
    int n_rays)
{
    __shared__ float cdf_s[16][68];   // cdf per block-ray slot (stride-padded)
    __shared__ int   mark_s[16][64];  // scatter slots

    const int tid  = threadIdx.x;
    const int lane = tid & 63;
    const int L    = lane & 15;       // lane within ray
    const int slot = tid >> 4;        // block ray slot 0..15
    const int ray  = blockIdx.x * 16 + slot;
    if (ray >= n_rays) return;        // n_rays % 16 == 0; no __syncthreads used

    // init early - LDS store latency hides under the exp chain below.
    *(int4*)(&mark_s[slot][4 * L]) = make_int4(0, 0, 0, 0);

    const float inv_s = (float)inv_s_ptr[0];
    const float s2 = -1.4426950408889634f * inv_s;   // exp2 scale (R19)

    // ---- loads: 4 consecutive samples per lane ----
    const float4 zc = *(const float4*)(z_vals + ray * 64 + 4 * L);
    const float4 sc = *(const float4*)(sdf    + ray * 64 + 4 * L);
    const float ox = rays_o[ray*3+0], oy = rays_o[ray*3+1], oz = rays_o[ray*3+2];
    const float dx = rays_d[ray*3+0], dy = rays_d[ray*3+1], dz_ = rays_d[ray*3+2];
    const float a  = ox*ox + oy*oy + oz*oz;
    const float b2 = 2.0f * (ox*dx + oy*dy + oz*dz_);

    // sample 4L+4 from lane+1 (wave_shl:1; garbage at L==15 -> masked below)
    // z4 stays DPP-EXACT: feeds the discontinuous r2<1 predicate.
    const float z4 = dpp_movf<0x130, 0xF>(zc.x, zc.x);
    const float s4 = dpp_movf<0x130, 0xF>(sc.x, sc.x);

    // scan-independent; LDS-pipe latency overlaps the exp chain.
    const float z0  = bperm(zc.x, lane & 48);
    const float z63 = bperm(zc.w, lane | 15);
    const float h   = (z63 - z0) * (1.0f / 63.0f);

    // uniform interval width (R19a) + R25a scale-fold constants
    const float rden = fast_rcp(h + 1e-5f);
    const float hs2  = 0.5f * s2;              // smid = (sv+sv')*hs2 = mid*s2
    const float q    = (0.5f * h) * (-s2);     // q = -hds2 > 0  (s2 < 0)
    const float G    = rden * q;               // cr2 = ds*G == cr*q
    const float lo2  = -1000.0f * q;           // clamp lower bound on cr2 scale

    const float zv[5] = {zc.x, zc.y, zc.z, zc.w, z4};
    const float sv[5] = {sc.x, sc.y, sc.z, sc.w, s4};

    // ---- inside-sphere predicates (exact z; discontinuous) ----
    float insf[4];
    {
        float r2a = fmaf(zv[0], zv[0] + b2, a);
        #pragma unroll
        for (int e = 0; e < 4; ++e) {
            const float r2b = fmaf(zv[e+1], zv[e+1] + b2, a);
            insf[e] = (fminf(r2a, r2b) < 1.0f) ? 1.0f : 0.0f;
            r2a = r2b;
        }
    }

    float cr2[4];
    #pragma unroll
    for (int e = 0; e < 4; ++e)
        cr2[e] = (sv[e+1] - sv[e]) * G;

    // prev-interval cos (scaled): element 3 of lane-1 (row_shr:1; 0 at start)
    float prev2 = dpp_movf<0x111, 0xF>(0.0f, cr2[3]);

    // ---- fused ratio-sigmoid/alpha/weight loop (R21 + R25) ----
    float t_part[4];
    float tsum = 0.0f, prun = 1.0f;
    #pragma unroll
    for (int e = 0; e < 4; ++e) {
        const float min2 = fminf(prev2, cr2[e]); prev2 = cr2[e];
        // c2 = q*cosv <= 0; aarg = smid + c2, barg = smid - c2 (cs = -c2)
        const float c2 = __builtin_amdgcn_fmed3f(min2, lo2, 0.0f) * insf[e];
        const float smid = (sv[e] + sv[e+1]) * hs2;   // mid*s2
        const float aarg = fminf(smid + c2, 60.0f);   // pe*s2, clamped
        const float barg = fminf(smid - c2, 60.0f);   // ne*s2, clamped
        const float A  = __builtin_amdgcn_exp2f(aarg);
        const float B  = __builtin_amdgcn_exp2f(barg);
        const float oB = 1.0f + B;
        const float Q  = (1.0f + A) * oB;
        const float num = fmaf(1e-5f, Q, B - A);
        const float den = fmaf(1e-5f, Q, oB);
        const float alpha = num * fast_rcp(den);
        float awe = alpha * prun;                 // alpha * exclusive-trans
        if (e == 3) awe = (L == 15) ? 0.0f : awe; // interval 63 doesn't exist
        t_part[e] = tsum;
        tsum += awe;
        prun *= (1.0000001f - alpha);             // (1-alpha+1e-7) folded
    }

    // ---- fused affine scan over the 16-lane row (R9) ----
    // (P,S)_L = inclusive combine of (prun_l, tsum_l); identity (1,0).
    float P = prun, S = tsum;
    {
        float Psh, Ssh;
        Psh = dpp_movf<0x111,0xF>(1.0f, P); Ssh = dpp_movf<0x111,0xF>(0.0f, S);
        S = fmaf(Psh, S, Ssh); P *= Psh;
        Psh = dpp_movf<0x112,0xF>(1.0f, P); Ssh = dpp_movf<0x112,0xF>(0.0f, S);
        S = fmaf(Psh, S, Ssh); P *= Psh;
        Psh = dpp_movf<0x114,0xF>(1.0f, P); Ssh = dpp_movf<0x114,0xF>(0.0f, S);
        S = fmaf(Psh, S, Ssh); P *= Psh;
        Psh = dpp_movf<0x118,0xF>(1.0f, P); Ssh = dpp_movf<0x118,0xF>(0.0f, S);
        S = fmaf(Psh, S, Ssh); P *= Psh;
    }
    const float Sex = dpp_movf<0x111, 0xF>(0.0f, S);  // sum over lanes < L
    const float Pex = dpp_movf<0x111, 0xF>(1.0f, P);  // transmittance into lane L

    const float T    = fmaf(63.0f, 1e-5f, bperm(S, lane | 15)); // + 63 offsets
    const float rtot = fast_rcp(T);

    // ---- cdf entries C[4L..4L+3]: (Sex + Pex*t_part[e] + (4L+e)*1e-5)/T ----
    const float kbase = (float)(4 * L);
    const float Sk    = fmaf(kbase, 1e-5f, Sex);
    float4 cvec;
    cvec.x = Sk * rtot;                                   // t_part[0] == 0
    cvec.y = (fmaf(Pex, t_part[1], Sk) + 1e-5f) * rtot;
    cvec.z = (fmaf(Pex, t_part[2], Sk) + 2e-5f) * rtot;
    cvec.w = (fmaf(Pex, t_part[3], Sk) + 3e-5f) * rtot;   // C[63] ~= 1 at L==15
    *(float4*)(&cdf_s[slot][4 * L]) = cvec;
    __builtin_amdgcn_wave_barrier();   // order: init+cdf before scatter

    // ---- scatter: entry j covers slots k >= ceil(64*C_j - 0.5) ----
    const float Cv[4] = {cvec.x, cvec.y, cvec.z, cvec.w};
    #pragma unroll
    for (int e = 0; e < 4; ++e) {
        const int kj = (int)ceilf(fmaf(64.0f, Cv[e], -0.5f));
        if (kj < 64) atomicMax(&mark_s[slot][kj], 4 * L + e);
    }
    __builtin_amdgcn_wave_barrier();   // order: scatter before gather

    // ---- inclusive max-scan over the 64 slots ----
    const int4 m4 = *(const int4*)(&mark_s[slot][4 * L]);
    const int i0 = m4.x;
    const int i1 = max(i0, m4.y);
    const int i2 = max(i1, m4.z);
    const int i3 = max(i2, m4.w);

    int ms = i3;
    ms = max(ms, dpp_movi<0x111, 0xF>(0, ms));
    ms = max(ms, dpp_movi<0x112, 0xF>(0, ms));
    ms = max(ms, dpp_movi<0x114, 0xF>(0, ms));
    ms = max(ms, dpp_movi<0x118, 0xF>(0, ms));
    const int Mex = dpp_movi<0x111, 0xF>(0, ms);   // max over lanes < L

    // ---- bl + interpolation merged: 2 LDS reads per query ----
    const float* cp = cdf_s[slot];
    const int iv[4] = {i0, i1, i2, i3};
    float ov[4];
    #pragma unroll
    for (int e = 0; e < 4; ++e) {
        const int   b  = min(max(Mex, iv[e]), 62);
        const float u  = fmaf(kbase + (float)e, 0.015625f, 0.0078125f);
        const float cb = cp[b];
        const float ca = cp[b + 1];
        float gap = ca - cb;
        gap = (gap < 1e-5f) ? 1.0f : gap;
        const float t = (u - cb) * fast_rcp(gap);
        ov[e] = fmaf((float)b + t, h, z0);   // z0 + h*(below + t)
    }
    *(float4*)(out + ray * 64 + 4 * L) = make_float4(ov[0], ov[1], ov[2], ov[3]);
}

extern "C" void kernel_launch(void* const* d_in, const int* in_sizes, int n_in,
                              void* d_out, int out_size, void* d_ws, size_t ws_size,
                              hipStream_t stream) {
    const float* rays_o = (const float*)d_in[0];
    const float* rays_d = (const float*)d_in[1];
    const float* z_vals = (const float*)d_in[2];
    const float* sdf    = (const float*)d_in[3];
    // d_in[4] = n_importance (== 64, hardcoded)
    const int*   inv_s  = (const int*)d_in[5];
    float* out = (float*)d_out;

    const int n_rays = in_sizes[0] / 3;          // 131072
    const int blocks = (n_rays + 15) / 16;       // 16 rays per 256-thr block

    neus_upsample_kernel<<<blocks, 256, 0, stream>>>(
        rays_o, rays_d, z_vals, sdf, inv_s, out, n_rays);
}